// Round 6
// baseline (225.357 us; speedup 1.0000x reference)
//
#include <hip/hip_runtime.h>

// out = A[j]*S + B[j],  j = floor(16*S) clamped to [0,15]
// A[j] = a[j]/Y, B[j] = (cum[j] - a[j]*j/16)/Y
// a[j] = 0.5 + 4.5*sigmoid(u[j]), Y = sum(a)/16, cum[j] = exclusive prefix(a)/16.
//
// Measured history (kernel-only time):
//   NT/NT  VPT=8 one-shot      : ~65 us  (R0/R4; sched_barrier pin null)
//   plain loads, any stores    : ~80 us  (R1/R3; LLC hit path slower than HBM)
//   persistent + reg ping-pong : ~65 us  (R5 null)
//   copy ceiling (m13 float4)  : 6.29 TB/s = 42.7 us for our 256 MiB
// Composite: bench iteration = fills(1074MB) + kernel(268MB) = 6.06 TB/s avg,
// 96% of copy ceiling; all remaining slack is the kernel's 4.1 vs 6.29 TB/s.
//
// R6 single change: burst shape. Every prior config issued 8-load/8-store
// bursts per wave (16 strided streams per block). The two things measured at
// 6.3-6.7 TB/s on this box (float4 copy, fills) are grid-stride with ONE
// access per iteration: 1R:1W naturally interleaved, MLP from TLP, two long
// contiguous streams per block. Mimic that exactly; keep NT (the only lever
// that measured real).

typedef float vf4 __attribute__((ext_vector_type(4)));

#define MSEG 16
#define BLK  256
#define NBLOCKS 2048    // 8 blocks/CU, grid-stride

__global__ __launch_bounds__(BLK) void mapping_kernel(
    const vf4* __restrict__ S4,
    const float* __restrict__ u,
    vf4* __restrict__ out4,
    int n4)
{
    __shared__ float sA[MSEG];
    __shared__ float sB[MSEG];

    const int tid = threadIdx.x;

    // Lane-parallel table build in wave 0 (shfl prefix sum, once per block).
    if (tid < 64) {
        float a = 0.0f;
        if (tid < MSEG) {
            float sig = 1.0f / (1.0f + expf(-u[tid]));
            a = 0.5f + 4.5f * sig;
        }
        float p = a;
        #pragma unroll
        for (int off = 1; off < MSEG; off <<= 1) {
            float t = __shfl_up(p, off, 64);
            if (tid >= off) p += t;
        }
        float total = __shfl(p, MSEG - 1, 64);
        if (tid < MSEG) {
            float invY = 16.0f / total;
            float cum  = (p - a) * (1.0f / 16.0f);
            sA[tid] = a * invY;
            sB[tid] = (cum - a * ((float)tid * (1.0f / 16.0f))) * invY;
        }
    }
    __syncthreads();

    // Canonical copy-style grid-stride: one vf4 in, one vf4 out per iteration.
    const int stride = gridDim.x * BLK;
    for (int i = blockIdx.x * BLK + tid; i < n4; i += stride) {
        const vf4 s = __builtin_nontemporal_load(&S4[i]);
        vf4 r;
        const int jx = min(max((int)(s.x * 16.0f), 0), 15);
        const int jy = min(max((int)(s.y * 16.0f), 0), 15);
        const int jz = min(max((int)(s.z * 16.0f), 0), 15);
        const int jw = min(max((int)(s.w * 16.0f), 0), 15);
        r.x = fmaf(s.x, sA[jx], sB[jx]);
        r.y = fmaf(s.y, sA[jy], sB[jy]);
        r.z = fmaf(s.z, sA[jz], sB[jz]);
        r.w = fmaf(s.w, sA[jw], sB[jw]);
        __builtin_nontemporal_store(r, &out4[i]);
    }
}

extern "C" void kernel_launch(void* const* d_in, const int* in_sizes, int n_in,
                              void* d_out, int out_size, void* d_ws, size_t ws_size,
                              hipStream_t stream)
{
    const vf4*  S4 = (const vf4*)d_in[0];        // [32,1024,1024] fp32
    const float* u = (const float*)d_in[1];      // [16] fp32
    // d_in[2] is M == 16, hardcoded.

    vf4* out4 = (vf4*)d_out;
    const int n4 = out_size / 4;                 // 8,388,608 float4s

    const int nwg = (n4 + BLK - 1) / BLK;
    const int grid = nwg < NBLOCKS ? (nwg > 0 ? nwg : 1) : NBLOCKS;
    mapping_kernel<<<grid, BLK, 0, stream>>>(S4, u, out4, n4);
}